// Round 19
// baseline (189.200 us; speedup 1.0000x reference)
//
#include <hip/hip_runtime.h>
#include <hip/hip_bf16.h>

#define NN 50000
#define NE 800000
#define NG 64
#define HID 64
#define NEG 0.2f
#define NPW 64          // nodes per wave in k_node
#define NBUCK 196       // ceil(NN/256) coarse buckets (dst>>8)
#define CHUNK 2048      // edges per k_bucket block
#define KC_CAP 6144     // per-bucket ebuf segment (mean 4081 + 32 sigma)

// ---- fp8 e4m3 branch-free encode (RNE) / decode ---------------------------
__device__ __forceinline__ unsigned int f2fp8(float f) {
    unsigned int sign = (__float_as_uint(f) >> 24) & 0x80;
    float a = fminf(fabsf(f), 448.f);
    unsigned int au = __float_as_uint(a);
    unsigned int r = au + 0x7FFFF + ((au >> 20) & 1);        // RNE to 3 man bits
    unsigned int enc_n = (((r >> 23) - 120) << 3) | ((r >> 20) & 7);
    float t = fmaf(a, 512.f, 12582912.f);                    // 1.5*2^23 magic add
    unsigned int enc_d = (unsigned int)(__float_as_int(t) - 0x4B400000);
    unsigned int enc = (au < 0x3C800000u) ? enc_d : enc_n;
    return sign | enc;
}
__device__ __forceinline__ float fp8dec(int i) {             // LUT init only
    int e = (i >> 3) & 15, m = i & 7;
    float v = e ? ldexpf((float)(8 + m), e - 10) : ldexpf((float)m, -9);
    return (i & 0x80) ? -v : v;
}

// ---- wave-shuffle inclusive scan over 256 block elements ------------------
// Returns inclusive prefix for index t; 1 barrier (plus caller's preceding one).
__device__ __forceinline__ int block_scan256(int v, int t, int* wtot4) {
    int lane = t & 63, wv = t >> 6;
    int inc = v;
    #pragma unroll
    for (int m = 1; m < 64; m <<= 1) {
        int u = __shfl_up(inc, m, 64);
        if (lane >= m) inc += u;
    }
    if (lane == 63) wtot4[wv] = inc;
    __syncthreads();
    int add = 0;
    #pragma unroll
    for (int ww = 0; ww < 3; ++ww) if (ww < wv) add += wtot4[ww];
    return inc + add;
}

// ---------------- K1: h(fp8) = x @ W ; a_s ; a_d ---------------------------
// r12-lean GEMM; fp8 encode decoupled into an LDS-staged epilogue phase so
// the 16 f2fp8 chains never coexist with the 16 live accumulators.
__global__ __launch_bounds__(256)
void k_xw(const float* __restrict__ x, const float* __restrict__ W,
          const float* __restrict__ att_s, const float* __restrict__ att_d,
          unsigned char* __restrict__ h8, float* __restrict__ as_, float* __restrict__ ad_,
          int* __restrict__ gcur) {
    __shared__ __align__(16) float sW[64][64];    // [k][c]
    __shared__ __align__(16) float sxT[64][68];   // [k][r]; reused as acc stage
    int t = threadIdx.x;
    if (blockIdx.x == 0 && t < NBUCK) gcur[t] = 0;
    int r0 = blockIdx.x * 64;
    for (int i = t; i < 4096; i += 256) sW[i >> 6][i & 63] = W[i];
    for (int i = t; i < 4096; i += 256) {
        int r = i >> 6, c = i & 63;
        int gr = r0 + r; if (gr >= NN) gr = NN - 1;
        sxT[c][r] = x[(size_t)gr * 64 + c];
    }
    __syncthreads();

    int tx = t & 15, ty = t >> 4;
    float4 asv = ((const float4*)att_s)[tx];
    float4 adv = ((const float4*)att_d)[tx];

    float acc[4][4] = {};
    #pragma unroll
    for (int k = 0; k < 64; ++k) {
        float4 a = *(const float4*)&sxT[k][4 * ty];
        float4 b = *(const float4*)&sW[k][4 * tx];
        float av[4] = {a.x, a.y, a.z, a.w};
        float bv[4] = {b.x, b.y, b.z, b.w};
        #pragma unroll
        for (int i = 0; i < 4; ++i)
            #pragma unroll
            for (int j = 0; j < 4; ++j)
                acc[i][j] += av[i] * bv[j];
    }
    __syncthreads();                               // sxT reads done everywhere

    #pragma unroll
    for (int i = 0; i < 4; ++i) {
        int rl = 4 * ty + i;
        *(float4*)&sxT[rl][4 * tx] =               // stash f32 row segment
            make_float4(acc[i][0], acc[i][1], acc[i][2], acc[i][3]);
        int r = r0 + rl;
        if (r < NN) {
            float ps = acc[i][0]*asv.x + acc[i][1]*asv.y + acc[i][2]*asv.z + acc[i][3]*asv.w;
            float pd = acc[i][0]*adv.x + acc[i][1]*adv.y + acc[i][2]*adv.z + acc[i][3]*adv.w;
            #pragma unroll
            for (int m = 1; m <= 8; m <<= 1) {
                ps += __shfl_xor(ps, m, 64);
                pd += __shfl_xor(pd, m, 64);
            }
            if (tx == 0) { as_[r] = ps; ad_[r] = pd; }
        }
    }
    __syncthreads();                               // stash complete

    // encode phase: tiny live set (4 floats + pack), acc dead
    for (int n = t; n < 1024; n += 256) {          // 1024 dwords = 64x64 fp8
        int row = n >> 4, c4 = (n & 15) * 4;
        int r = r0 + row;
        if (r < NN) {
            float4 v = *(const float4*)&sxT[row][c4];
            unsigned int p = f2fp8(v.x) | (f2fp8(v.y) << 8)
                           | (f2fp8(v.z) << 16) | (f2fp8(v.w) << 24);
            *(unsigned int*)&h8[(size_t)r * 64 + c4] = p;
        }
    }
}

// ---------------- Pass B: bucket sort + edge-weight precompute ------------
__global__ __launch_bounds__(256)
void k_bucket(const int* __restrict__ src, const int* __restrict__ dst,
              const float* __restrict__ as_, const float* __restrict__ ad_,
              int* __restrict__ gcur, int2* __restrict__ ebuf) {
    __shared__ int lhist[256], loff[256], lcur[256], gbase[256];
    __shared__ int wtot[4];
    __shared__ int2 lsort[CHUNK];
    __shared__ unsigned char lbuck[CHUNK];
    int t = threadIdx.x;
    int base = blockIdx.x * CHUNK;
    int cnt = NE - base; if (cnt > CHUNK) cnt = CHUNK; if (cnt < 0) cnt = 0;

    int ds[8], ss[8];
    float ex[8];
    int nv = 0;
    #pragma unroll
    for (int j = 0; j < 8; ++j) {
        int e = base + j * 256 + t;
        if (e < NE) { ds[nv] = dst[e]; ss[nv] = src[e]; ++nv; }
    }
    for (int j = 0; j < nv; ++j) {
        float e = as_[ss[j]] + ad_[ds[j]];
        e = e >= 0.f ? e : NEG * e;
        ex[j] = __expf(e);
    }
    lhist[t] = 0;
    __syncthreads();
    for (int j = 0; j < nv; ++j) atomicAdd(&lhist[ds[j] >> 8], 1);
    __syncthreads();
    int hv = lhist[t];
    int incl = block_scan256(hv, t, wtot);        // 1 barrier inside
    loff[t] = incl - hv;                          // exclusive
    lcur[t] = 0;
    __syncthreads();
    for (int j = 0; j < nv; ++j) {
        int b = ds[j] >> 8;
        int r = atomicAdd(&lcur[b], 1);
        int slot = loff[b] + r;
        lsort[slot] = make_int2((ss[j] << 8) | (ds[j] & 255), __float_as_int(ex[j]));
        lbuck[slot] = (unsigned char)b;
    }
    if (t < NBUCK) {
        int c = lhist[t];
        gbase[t] = c ? atomicAdd(&gcur[t], c) : 0;    // offset WITHIN bucket t
    }
    __syncthreads();
    for (int i = t; i < cnt; i += 256) {
        int b = lbuck[i];
        ebuf[b * KC_CAP + gbase[b] + (i - loff[b])] = lsort[i];
    }
}

// ---------------- Pass C: exact CSR within each bucket --------------------
__global__ __launch_bounds__(256)
void k_csr(const int* __restrict__ gcur, const int2* __restrict__ ebuf,
           int2* __restrict__ csr2, int* __restrict__ cursor, int* __restrict__ deg) {
    __shared__ int lhist[256], loff[256], lcur[256], bix[256];
    __shared__ int wtot[4];
    __shared__ int2 lsrc[KC_CAP];
    int t = threadIdx.x;
    int b = blockIdx.x;

    int sz_t = (t < NBUCK) ? gcur[t] : 0;
    bix[t] = block_scan256(sz_t, t, wtot);        // inclusive over bucket sizes
    lhist[t] = 0;
    __syncthreads();
    int sz = gcur[b];
    int gb = bix[b] - sz;                          // dense CSR base (exclusive)
    const int2* seg = ebuf + b * KC_CAP;

    for (int i = t; i < sz; i += 256)
        atomicAdd(&lhist[seg[i].x & 255], 1);
    __syncthreads();
    int hv = lhist[t];
    int incl = block_scan256(hv, t, wtot);        // 1 barrier inside
    loff[t] = incl - hv;
    lcur[t] = 0;
    __syncthreads();
    for (int i = t; i < sz; i += 256) {
        int2 w = seg[i];
        int dl = w.x & 255;
        int r = atomicAdd(&lcur[dl], 1);
        lsrc[loff[dl] + r] = make_int2(w.x >> 8, w.y);
    }
    __syncthreads();
    for (int i = t; i < sz; i += 256)
        csr2[gb + i] = lsrc[i];
    int d = b * 256 + t;
    if (d < NN) {
        deg[d] = hv;
        cursor[d] = gb + loff[t] + hv;             // end offset
    }
}

// ---------------- K2': gather, 8 edges/iter, fp8 h + LDS LUT decode -------
__global__ __launch_bounds__(256)
void k_gather(const int2* __restrict__ csr2, const int* __restrict__ cursor,
              const int* __restrict__ deg, const unsigned char* __restrict__ h8,
              const float* __restrict__ as_, const float* __restrict__ ad_,
              const float* __restrict__ bias, float* __restrict__ g,
              float* __restrict__ poolz) {
    __shared__ float lut[256];
    int t = threadIdx.x;
    if (t < 256) lut[t] = fp8dec(t);
    if (blockIdx.x == 0) {
        for (int i = t; i < NG * HID + NG; i += 256) poolz[i] = 0.f;
    }
    __syncthreads();
    int wave = t >> 6, lane = t & 63;
    int d = blockIdx.x * 4 + wave;
    if (d >= NN) return;
    int grp = lane >> 3;          // edge group 0..7
    int cc  = lane & 7;           // channel slice (8 channels each)
    int cend = cursor[d];
    int nd   = deg[d];
    int cbeg = cend - nd;

    float acc[8] = {};
    float den = 0.f;

    // self-loop (weight nonzero only in group 0; summed once by the reduce)
    {
        float e0 = as_[d] + ad_[d];
        e0 = e0 >= 0.f ? e0 : NEG * e0;
        float ex0 = (grp == 0) ? __expf(e0) : 0.f;
        den += ex0;
        uint2 v = *(const uint2*)&h8[(size_t)d * 64 + 8 * cc];
        acc[0] += lut[v.x & 255] * ex0;         acc[1] += lut[(v.x >> 8) & 255] * ex0;
        acc[2] += lut[(v.x >> 16) & 255] * ex0; acc[3] += lut[(v.x >> 24) & 255] * ex0;
        acc[4] += lut[v.y & 255] * ex0;         acc[5] += lut[(v.y >> 8) & 255] * ex0;
        acc[6] += lut[(v.y >> 16) & 255] * ex0; acc[7] += lut[(v.y >> 24) & 255] * ex0;
    }

    for (int c0 = 0; c0 < nd; c0 += 8) {
        int  e  = c0 + grp;
        bool ok = e < nd;
        int  ci = cbeg + (ok ? e : (nd - 1));
        int2 se = csr2[ci];                       // coalesced (s, ex)
        int    s  = se.x;
        float  ex = ok ? __int_as_float(se.y) : 0.f;
        den += ex;
        uint2 v = *(const uint2*)&h8[(size_t)s * 64 + 8 * cc];   // 8B/lane, 64B row
        acc[0] += lut[v.x & 255] * ex;         acc[1] += lut[(v.x >> 8) & 255] * ex;
        acc[2] += lut[(v.x >> 16) & 255] * ex; acc[3] += lut[(v.x >> 24) & 255] * ex;
        acc[4] += lut[v.y & 255] * ex;         acc[5] += lut[(v.y >> 8) & 255] * ex;
        acc[6] += lut[(v.y >> 16) & 255] * ex; acc[7] += lut[(v.y >> 24) & 255] * ex;
    }

    #pragma unroll
    for (int m = 8; m <= 32; m <<= 1) {
        den += __shfl_xor(den, m, 64);
        #pragma unroll
        for (int k = 0; k < 8; ++k) acc[k] += __shfl_xor(acc[k], m, 64);
    }

    if (grp == 0) {                               // 8 lanes write the row
        float inv = 1.f / den;
        float4 b0 = ((const float4*)bias)[2 * cc];
        float4 b1 = ((const float4*)bias)[2 * cc + 1];
        float4 o0, o1;
        o0.x = fmaxf(acc[0] * inv + b0.x, 0.f);
        o0.y = fmaxf(acc[1] * inv + b0.y, 0.f);
        o0.z = fmaxf(acc[2] * inv + b0.z, 0.f);
        o0.w = fmaxf(acc[3] * inv + b0.w, 0.f);
        o1.x = fmaxf(acc[4] * inv + b1.x, 0.f);
        o1.y = fmaxf(acc[5] * inv + b1.y, 0.f);
        o1.z = fmaxf(acc[6] * inv + b1.z, 0.f);
        o1.w = fmaxf(acc[7] * inv + b1.w, 0.f);
        *(float4*)&g[(size_t)d * 64 + 8 * cc]     = o0;
        *(float4*)&g[(size_t)d * 64 + 8 * cc + 4] = o1;
    }
}

// ---------------- K3: pooled partial sums (batch sorted, run-length) ------
__global__ __launch_bounds__(256)
void k_node(const float* __restrict__ g, const int* __restrict__ batch,
            float* __restrict__ pooled, float* __restrict__ cnt) {
    int t = threadIdx.x;
    int wave = t >> 6, lane = t & 63;
    int n0 = (blockIdx.x * 4 + wave) * NPW;
    if (n0 >= NN) return;
    int n1 = n0 + NPW; if (n1 > NN) n1 = NN;
    float acc = 0.f, c = 0.f;
    int cur = batch[n0];
    for (int n = n0; n < n1; ++n) {
        int gr = batch[n];
        if (gr != cur) {
            atomicAdd(&pooled[cur * 64 + lane], acc);
            if (lane == 0) atomicAdd(&cnt[cur], c);
            acc = 0.f; c = 0.f; cur = gr;
        }
        acc += g[(size_t)n * 64 + lane];
        c += 1.f;
    }
    atomicAdd(&pooled[cur * 64 + lane], acc);
    if (lane == 0) atomicAdd(&cnt[cur], c);
}

// ---------------- K4: mean + MLP + sigmoid (single block) ------------------
__global__ __launch_bounds__(256)
void k_final(const float* __restrict__ pooled, const float* __restrict__ cnt,
             const float* __restrict__ w1, const float* __restrict__ b1,
             const float* __restrict__ w2, const float* __restrict__ b2,
             float* __restrict__ out) {
    __shared__ float sp[64][65];
    __shared__ float sz[64][65];
    int t = threadIdx.x;
    for (int i = t; i < 4096; i += 256) {
        int g = i >> 6, c = i & 63;
        sp[g][c] = pooled[i] / fmaxf(cnt[g], 1.0f);
    }
    __syncthreads();
    for (int i = t; i < 4096; i += 256) {
        int g = i >> 6, c = i & 63;
        float acc = b1[c];
        #pragma unroll
        for (int k = 0; k < 64; ++k) acc += sp[g][k] * w1[k * 64 + c];
        sz[g][c] = fmaxf(acc, 0.f);
    }
    __syncthreads();
    if (t < 64) {
        float acc = b2[0];
        #pragma unroll
        for (int c = 0; c < 64; ++c) acc += sz[t][c] * w2[c];
        out[t] = 1.f / (1.f + __expf(-acc));
    }
}

extern "C" void kernel_launch(void* const* d_in, const int* in_sizes, int n_in,
                              void* d_out, int out_size, void* d_ws, size_t ws_size,
                              hipStream_t stream) {
    const float* x     = (const float*)d_in[0];
    const int*   ei    = (const int*)d_in[1];   // [2, NE] flat: src row then dst row
    const int*   batch = (const int*)d_in[2];
    const float* W     = (const float*)d_in[3];
    const float* att_s = (const float*)d_in[4];
    const float* att_d = (const float*)d_in[5];
    const float* bias  = (const float*)d_in[6];
    const float* w1    = (const float*)d_in[7];
    const float* b1    = (const float*)d_in[8];
    const float* w2    = (const float*)d_in[9];
    const float* b2    = (const float*)d_in[10];
    float* out = (float*)d_out;

    const int* src = ei;
    const int* dst = ei + NE;

    // workspace layout
    unsigned char* h8 = (unsigned char*)d_ws;        // NN*64 fp8  (3.2 MB)
    float* as_    = (float*)(h8 + (size_t)NN * HID); // NN
    float* ad_    = as_ + NN;                        // NN
    float* g      = ad_ + NN;                        // NN*64 f32 (12.8 MB, ebuf aliases)
    float* pooled = g + (size_t)NN * HID;            // NG*64
    float* cntp   = pooled + NG * HID;               // NG
    int*   deg    = (int*)(cntp + NG);               // NN
    int*   cursor = deg + NN;                        // NN
    int2*  csr2   = (int2*)(cursor + NN);            // NE int2 (6.4 MB)
    int*   gcur   = (int*)(csr2 + NE);               // NBUCK
    int2*  ebuf   = (int2*)g;                        // NBUCK*KC_CAP int2 (9.6 MB < 12.8)

    k_xw<<<(NN + 63) / 64, 256, 0, stream>>>(x, W, att_s, att_d, h8, as_, ad_, gcur);

    k_bucket<<<(NE + CHUNK - 1) / CHUNK, 256, 0, stream>>>(src, dst, as_, ad_, gcur, ebuf);
    k_csr<<<NBUCK, 256, 0, stream>>>(gcur, ebuf, csr2, cursor, deg);

    k_gather<<<(NN + 3) / 4, 256, 0, stream>>>(csr2, cursor, deg, h8, as_, ad_, bias, g, pooled);

    k_node<<<(NN / (4 * NPW)) + 1, 256, 0, stream>>>(g, batch, pooled, cntp);

    k_final<<<1, 256, 0, stream>>>(pooled, cntp, w1, b1, w2, b2, out);
}

// Round 20
// 137.287 us; speedup vs baseline: 1.3781x; 1.3781x over previous
//
#include <hip/hip_runtime.h>
#include <hip/hip_bf16.h>

#define NN 50000
#define NE 800000
#define NG 64
#define HID 64
#define NEG 0.2f
#define NPW 64          // nodes per wave in k_node
#define NBUCK 196       // ceil(NN/256) coarse buckets (dst>>8)
#define CHUNK 2048      // edges per k_bucket block
#define KC_CAP 6144     // per-bucket ebuf segment (mean 4081 + 32 sigma)

// ---- bf16 helpers ---------------------------------------------------------
__device__ __forceinline__ unsigned short f2bf(float f) {
    unsigned int u = __float_as_uint(f);
    unsigned int r = (u + 0x7FFF + ((u >> 16) & 1)) >> 16;   // RNE
    return (unsigned short)r;
}
__device__ __forceinline__ float bf2f(unsigned short b) {
    return __uint_as_float(((unsigned int)b) << 16);
}

// ---- fp8 e4m3 branch-free encode (RNE) / decode ---------------------------
// NOTE (r15/r17/r19): f2fp8 inside k_xw triggers a 256-VGPR spill; it MUST
// stay in its own kernel (k_enc).
__device__ __forceinline__ unsigned int f2fp8(float f) {
    unsigned int sign = (__float_as_uint(f) >> 24) & 0x80;
    float a = fminf(fabsf(f), 448.f);
    unsigned int au = __float_as_uint(a);
    unsigned int r = au + 0x7FFFF + ((au >> 20) & 1);        // RNE to 3 man bits
    unsigned int enc_n = (((r >> 23) - 120) << 3) | ((r >> 20) & 7);
    float t = fmaf(a, 512.f, 12582912.f);                    // 1.5*2^23 magic add
    unsigned int enc_d = (unsigned int)(__float_as_int(t) - 0x4B400000);
    unsigned int enc = (au < 0x3C800000u) ? enc_d : enc_n;
    return sign | enc;
}
__device__ __forceinline__ float fp8dec(int i) {             // LUT init only
    int e = (i >> 3) & 15, m = i & 7;
    float v = e ? ldexpf((float)(8 + m), e - 10) : ldexpf((float)m, -9);
    return (i & 0x80) ? -v : v;
}

// ---------------- K1: h(bf16) = x @ W ; a_s ; a_d --------------------------
// Exact r12 structure (measured lean). Block 0 zeroes gcur.
__global__ __launch_bounds__(256)
void k_xw(const float* __restrict__ x, const float* __restrict__ W,
          const float* __restrict__ att_s, const float* __restrict__ att_d,
          unsigned short* __restrict__ hb, float* __restrict__ as_, float* __restrict__ ad_,
          int* __restrict__ gcur) {
    __shared__ __align__(16) float sW[64][64];    // [k][c]
    __shared__ __align__(16) float sxT[64][68];   // [k][r]
    int t = threadIdx.x;
    if (blockIdx.x == 0 && t < NBUCK) gcur[t] = 0;
    int r0 = blockIdx.x * 64;
    for (int i = t; i < 4096; i += 256) sW[i >> 6][i & 63] = W[i];
    for (int i = t; i < 4096; i += 256) {
        int r = i >> 6, c = i & 63;
        int gr = r0 + r; if (gr >= NN) gr = NN - 1;
        sxT[c][r] = x[(size_t)gr * 64 + c];
    }
    __syncthreads();

    int tx = t & 15, ty = t >> 4;
    float4 asv = ((const float4*)att_s)[tx];
    float4 adv = ((const float4*)att_d)[tx];

    float acc[4][4] = {};
    #pragma unroll
    for (int k = 0; k < 64; ++k) {
        float4 a = *(const float4*)&sxT[k][4 * ty];
        float4 b = *(const float4*)&sW[k][4 * tx];
        float av[4] = {a.x, a.y, a.z, a.w};
        float bv[4] = {b.x, b.y, b.z, b.w};
        #pragma unroll
        for (int i = 0; i < 4; ++i)
            #pragma unroll
            for (int j = 0; j < 4; ++j)
                acc[i][j] += av[i] * bv[j];
    }

    #pragma unroll
    for (int i = 0; i < 4; ++i) {
        int r = r0 + 4 * ty + i;
        if (r < NN) {
            ushort4 hv;
            hv.x = f2bf(acc[i][0]); hv.y = f2bf(acc[i][1]);
            hv.z = f2bf(acc[i][2]); hv.w = f2bf(acc[i][3]);
            *(ushort4*)&hb[(size_t)r * 64 + 4 * tx] = hv;     // 8B store
            float ps = acc[i][0]*asv.x + acc[i][1]*asv.y + acc[i][2]*asv.z + acc[i][3]*asv.w;
            float pd = acc[i][0]*adv.x + acc[i][1]*adv.y + acc[i][2]*adv.z + acc[i][3]*adv.w;
            #pragma unroll
            for (int m = 1; m <= 8; m <<= 1) {
                ps += __shfl_xor(ps, m, 64);
                pd += __shfl_xor(pd, m, 64);
            }
            if (tx == 0) { as_[r] = ps; ad_[r] = pd; }
        }
    }
}

// ---------------- K1b: bf16 -> fp8 streaming convert (r18, lean) -----------
__global__ __launch_bounds__(256)
void k_enc(const unsigned short* __restrict__ hb, unsigned char* __restrict__ h8) {
    int i = blockIdx.x * 256 + threadIdx.x;       // one dword (4 elems) each
    if (i < NN * HID / 4) {
        ushort4 v = ((const ushort4*)hb)[i];
        unsigned int p = f2fp8(bf2f(v.x)) | (f2fp8(bf2f(v.y)) << 8)
                       | (f2fp8(bf2f(v.z)) << 16) | (f2fp8(bf2f(v.w)) << 24);
        ((unsigned int*)h8)[i] = p;
    }
}

// ---------------- Pass B: bucket sort, 4B packed entries (r12 lean) -------
__global__ __launch_bounds__(256)
void k_bucket(const int* __restrict__ src, const int* __restrict__ dst,
              int* __restrict__ gcur, int* __restrict__ ebuf) {
    __shared__ int lhist[256], lscan[256], loff[256], lcur[256], gbase[256];
    __shared__ int lsort[CHUNK];
    __shared__ unsigned char lbuck[CHUNK];
    int t = threadIdx.x;
    int base = blockIdx.x * CHUNK;
    int cnt = NE - base; if (cnt > CHUNK) cnt = CHUNK; if (cnt < 0) cnt = 0;

    int ds[8], ss[8];
    int nv = 0;
    #pragma unroll
    for (int j = 0; j < 8; ++j) {
        int e = base + j * 256 + t;
        if (e < NE) { ds[nv] = dst[e]; ss[nv] = src[e]; ++nv; }
    }
    lhist[t] = 0;
    __syncthreads();
    for (int j = 0; j < nv; ++j) atomicAdd(&lhist[ds[j] >> 8], 1);
    __syncthreads();
    lscan[t] = lhist[t];
    __syncthreads();
    for (int off = 1; off < 256; off <<= 1) {
        int u = (t >= off) ? lscan[t - off] : 0;
        __syncthreads();
        lscan[t] += u;
        __syncthreads();
    }
    loff[t] = lscan[t] - lhist[t];   // exclusive
    lcur[t] = 0;
    __syncthreads();
    for (int j = 0; j < nv; ++j) {
        int b = ds[j] >> 8;
        int r = atomicAdd(&lcur[b], 1);
        int slot = loff[b] + r;
        lsort[slot] = (ss[j] << 8) | (ds[j] & 255);   // src<50000 fits in 24b
        lbuck[slot] = (unsigned char)b;
    }
    if (t < NBUCK) {
        int c = lhist[t];
        gbase[t] = c ? atomicAdd(&gcur[t], c) : 0;    // offset WITHIN bucket t
    }
    __syncthreads();
    for (int i = t; i < cnt; i += 256) {
        int b = lbuck[i];
        ebuf[b * KC_CAP + gbase[b] + (i - loff[b])] = lsort[i];
    }
}

// ---------------- Pass C: exact CSR within each bucket (int entries) ------
__global__ __launch_bounds__(256)
void k_csr(const int* __restrict__ gcur, const int* __restrict__ ebuf,
           int* __restrict__ csr, int* __restrict__ cursor, int* __restrict__ deg) {
    __shared__ int lhist[256], lscan[256], loff[256], lcur[256], bscan[256];
    __shared__ int lsrc[KC_CAP];
    int t = threadIdx.x;
    int b = blockIdx.x;

    bscan[t] = (t < NBUCK) ? gcur[t] : 0;     // bucket sizes
    __syncthreads();
    for (int off = 1; off < 256; off <<= 1) {
        int u = (t >= off) ? bscan[t - off] : 0;
        __syncthreads();
        bscan[t] += u;
        __syncthreads();
    }
    int sz = gcur[b];
    int gb = bscan[b] - sz;                    // dense CSR base (exclusive)
    const int* seg = ebuf + b * KC_CAP;

    lhist[t] = 0;
    __syncthreads();
    for (int i = t; i < sz; i += 256)
        atomicAdd(&lhist[seg[i] & 255], 1);
    __syncthreads();
    lscan[t] = lhist[t];
    __syncthreads();
    for (int off = 1; off < 256; off <<= 1) {
        int u = (t >= off) ? lscan[t - off] : 0;
        __syncthreads();
        lscan[t] += u;
        __syncthreads();
    }
    loff[t] = lscan[t] - lhist[t];
    lcur[t] = 0;
    __syncthreads();
    for (int i = t; i < sz; i += 256) {
        int w = seg[i];
        int dl = w & 255;
        int r = atomicAdd(&lcur[dl], 1);
        lsrc[loff[dl] + r] = w >> 8;
    }
    __syncthreads();
    for (int i = t; i < sz; i += 256)
        csr[gb + i] = lsrc[i];
    int d = b * 256 + t;
    if (d < NN) {
        deg[d] = lhist[t];
        cursor[d] = gb + loff[t] + lhist[t];   // end offset
    }
}

// ---------------- K2': gather, 8 edges/iter, fp8 h + in-loop exp ----------
// Working set: h8 3.2MB + as_ 200KB + csr 3.2MB -> all fit 4MB per-XCD L2.
__global__ __launch_bounds__(256)
void k_gather(const int* __restrict__ csr, const int* __restrict__ cursor,
              const int* __restrict__ deg, const unsigned char* __restrict__ h8,
              const float* __restrict__ as_, const float* __restrict__ ad_,
              const float* __restrict__ bias, float* __restrict__ g,
              float* __restrict__ poolz) {
    __shared__ float lut[256];
    int t = threadIdx.x;
    if (t < 256) lut[t] = fp8dec(t);
    if (blockIdx.x == 0) {
        for (int i = t; i < NG * HID + NG; i += 256) poolz[i] = 0.f;
    }
    __syncthreads();
    int wave = t >> 6, lane = t & 63;
    int d = blockIdx.x * 4 + wave;
    if (d >= NN) return;
    int grp = lane >> 3;          // edge group 0..7
    int cc  = lane & 7;           // channel slice (8 channels each)
    int cend = cursor[d];
    int nd   = deg[d];
    int cbeg = cend - nd;
    float adv = ad_[d];

    float acc[8] = {};
    float den = 0.f;

    // self-loop (weight nonzero only in group 0; summed once by the reduce)
    {
        float e0 = as_[d] + adv;
        e0 = e0 >= 0.f ? e0 : NEG * e0;
        float ex0 = (grp == 0) ? __expf(e0) : 0.f;
        den += ex0;
        uint2 v = *(const uint2*)&h8[(size_t)d * 64 + 8 * cc];
        acc[0] += lut[v.x & 255] * ex0;         acc[1] += lut[(v.x >> 8) & 255] * ex0;
        acc[2] += lut[(v.x >> 16) & 255] * ex0; acc[3] += lut[(v.x >> 24) & 255] * ex0;
        acc[4] += lut[v.y & 255] * ex0;         acc[5] += lut[(v.y >> 8) & 255] * ex0;
        acc[6] += lut[(v.y >> 16) & 255] * ex0; acc[7] += lut[(v.y >> 24) & 255] * ex0;
    }

    for (int c0 = 0; c0 < nd; c0 += 8) {
        int  e  = c0 + grp;
        bool ok = e < nd;
        int  ci = cbeg + (ok ? e : (nd - 1));
        int    s = csr[ci];                       // 8 edges / coalesced dwords
        float  a = as_[s];                        // L2-resident random 4B
        float av = a + adv;
        av = av >= 0.f ? av : NEG * av;
        float ex = ok ? __expf(av) : 0.f;
        den += ex;
        uint2 v = *(const uint2*)&h8[(size_t)s * 64 + 8 * cc];   // 8B/lane, 64B row
        acc[0] += lut[v.x & 255] * ex;         acc[1] += lut[(v.x >> 8) & 255] * ex;
        acc[2] += lut[(v.x >> 16) & 255] * ex; acc[3] += lut[(v.x >> 24) & 255] * ex;
        acc[4] += lut[v.y & 255] * ex;         acc[5] += lut[(v.y >> 8) & 255] * ex;
        acc[6] += lut[(v.y >> 16) & 255] * ex; acc[7] += lut[(v.y >> 24) & 255] * ex;
    }

    #pragma unroll
    for (int m = 8; m <= 32; m <<= 1) {
        den += __shfl_xor(den, m, 64);
        #pragma unroll
        for (int k = 0; k < 8; ++k) acc[k] += __shfl_xor(acc[k], m, 64);
    }

    if (grp == 0) {                               // 8 lanes write the row
        float inv = 1.f / den;
        float4 b0 = ((const float4*)bias)[2 * cc];
        float4 b1 = ((const float4*)bias)[2 * cc + 1];
        float4 o0, o1;
        o0.x = fmaxf(acc[0] * inv + b0.x, 0.f);
        o0.y = fmaxf(acc[1] * inv + b0.y, 0.f);
        o0.z = fmaxf(acc[2] * inv + b0.z, 0.f);
        o0.w = fmaxf(acc[3] * inv + b0.w, 0.f);
        o1.x = fmaxf(acc[4] * inv + b1.x, 0.f);
        o1.y = fmaxf(acc[5] * inv + b1.y, 0.f);
        o1.z = fmaxf(acc[6] * inv + b1.z, 0.f);
        o1.w = fmaxf(acc[7] * inv + b1.w, 0.f);
        *(float4*)&g[(size_t)d * 64 + 8 * cc]     = o0;
        *(float4*)&g[(size_t)d * 64 + 8 * cc + 4] = o1;
    }
}

// ---------------- K3: pooled partial sums (batch sorted, run-length) ------
__global__ __launch_bounds__(256)
void k_node(const float* __restrict__ g, const int* __restrict__ batch,
            float* __restrict__ pooled, float* __restrict__ cnt) {
    int t = threadIdx.x;
    int wave = t >> 6, lane = t & 63;
    int n0 = (blockIdx.x * 4 + wave) * NPW;
    if (n0 >= NN) return;
    int n1 = n0 + NPW; if (n1 > NN) n1 = NN;
    float acc = 0.f, c = 0.f;
    int cur = batch[n0];
    for (int n = n0; n < n1; ++n) {
        int gr = batch[n];
        if (gr != cur) {
            atomicAdd(&pooled[cur * 64 + lane], acc);
            if (lane == 0) atomicAdd(&cnt[cur], c);
            acc = 0.f; c = 0.f; cur = gr;
        }
        acc += g[(size_t)n * 64 + lane];
        c += 1.f;
    }
    atomicAdd(&pooled[cur * 64 + lane], acc);
    if (lane == 0) atomicAdd(&cnt[cur], c);
}

// ---------------- K4: mean + MLP + sigmoid (single block) ------------------
__global__ __launch_bounds__(256)
void k_final(const float* __restrict__ pooled, const float* __restrict__ cnt,
             const float* __restrict__ w1, const float* __restrict__ b1,
             const float* __restrict__ w2, const float* __restrict__ b2,
             float* __restrict__ out) {
    __shared__ float sp[64][65];
    __shared__ float sz[64][65];
    int t = threadIdx.x;
    for (int i = t; i < 4096; i += 256) {
        int g = i >> 6, c = i & 63;
        sp[g][c] = pooled[i] / fmaxf(cnt[g], 1.0f);
    }
    __syncthreads();
    for (int i = t; i < 4096; i += 256) {
        int g = i >> 6, c = i & 63;
        float acc = b1[c];
        #pragma unroll
        for (int k = 0; k < 64; ++k) acc += sp[g][k] * w1[k * 64 + c];
        sz[g][c] = fmaxf(acc, 0.f);
    }
    __syncthreads();
    if (t < 64) {
        float acc = b2[0];
        #pragma unroll
        for (int c = 0; c < 64; ++c) acc += sz[t][c] * w2[c];
        out[t] = 1.f / (1.f + __expf(-acc));
    }
}

extern "C" void kernel_launch(void* const* d_in, const int* in_sizes, int n_in,
                              void* d_out, int out_size, void* d_ws, size_t ws_size,
                              hipStream_t stream) {
    const float* x     = (const float*)d_in[0];
    const int*   ei    = (const int*)d_in[1];   // [2, NE] flat: src row then dst row
    const int*   batch = (const int*)d_in[2];
    const float* W     = (const float*)d_in[3];
    const float* att_s = (const float*)d_in[4];
    const float* att_d = (const float*)d_in[5];
    const float* bias  = (const float*)d_in[6];
    const float* w1    = (const float*)d_in[7];
    const float* b1    = (const float*)d_in[8];
    const float* w2    = (const float*)d_in[9];
    const float* b2    = (const float*)d_in[10];
    float* out = (float*)d_out;

    const int* src = ei;
    const int* dst = ei + NE;

    // workspace layout
    unsigned char*  h8 = (unsigned char*)d_ws;                       // 3.2 MB
    unsigned short* hb = (unsigned short*)(h8 + (size_t)NN * HID);   // 6.4 MB
    float* as_    = (float*)(hb + (size_t)NN * HID); // NN
    float* ad_    = as_ + NN;                        // NN
    float* g      = ad_ + NN;                        // NN*64 f32 (12.8 MB, ebuf aliases)
    float* pooled = g + (size_t)NN * HID;            // NG*64
    float* cntp   = pooled + NG * HID;               // NG
    int*   deg    = (int*)(cntp + NG);               // NN
    int*   cursor = deg + NN;                        // NN
    int*   csr    = cursor + NN;                     // NE int (3.2 MB)
    int*   gcur   = csr + NE;                        // NBUCK
    int*   ebuf   = (int*)g;                         // NBUCK*KC_CAP int (4.8 MB < 12.8)

    k_xw<<<(NN + 63) / 64, 256, 0, stream>>>(x, W, att_s, att_d, hb, as_, ad_, gcur);

    k_enc<<<(NN * HID / 4 + 255) / 256, 256, 0, stream>>>(hb, h8);

    k_bucket<<<(NE + CHUNK - 1) / CHUNK, 256, 0, stream>>>(src, dst, gcur, ebuf);
    k_csr<<<NBUCK, 256, 0, stream>>>(gcur, ebuf, csr, cursor, deg);

    k_gather<<<(NN + 3) / 4, 256, 0, stream>>>(csr, cursor, deg, h8, as_, ad_, bias, g, pooled);

    k_node<<<(NN / (4 * NPW)) + 1, 256, 0, stream>>>(g, batch, pooled, cntp);

    k_final<<<1, 256, 0, stream>>>(pooled, cntp, w1, b1, w2, b2, out);
}